// Round 5
// baseline (200.506 us; speedup 1.0000x reference)
//
#include <hip/hip_runtime.h>

// Problem constants (fixed by the reference harness).
#define BB 64
#define SS 2048
#define DD 256
#define NSL 8          // D-slices; one block per (doc, slice)
#define CPS (DD / NSL) // 32 columns per block
#define NT 512         // threads per block (8 waves)
#define NW (NT / 64)

#define FLT_BIG 3.4028234e38f

// ---------------------------------------------------------------------------
// One block = (slice sl, doc b). 512 threads: d4 = tid&7 picks a float4
// column within the slice, srow = tid>>3 in [0,64) staggers rows; thread
// loops s = srow + 64k (32 iters). Each wave-load covers 8 rows x 128 B
// contiguous segments (one L2 line each). All five stats finish inside the
// block: butterfly-combine the 8 row-groups per wave (xor 32/16/8), one LDS
// combine across 8 waves, 32 threads write the slice's outputs. 512 blocks
// (2/CU minimum, up to 4 co-resident) so staging + reduction tails of one
// block hide under streaming of others — R4's 256-block grid had exactly
// 1 block/CU and nothing to overlap with.
// Zero inter-block communication (R3's device-fence pattern cost 3x).
// ---------------------------------------------------------------------------
__global__ __launch_bounds__(NT) void fused_kernel(
    const int* __restrict__ chunk, const float* __restrict__ enc,
    const float* __restrict__ idf, float* __restrict__ out) {
  const int sl = blockIdx.x;
  const int b = blockIdx.y;
  const int tid = threadIdx.x;
  const int lane = tid & 63;
  const int wid = tid >> 6;
  const int d4 = tid & 7;    // float4 column within slice
  const int srow = tid >> 3; // 0..63

  __shared__ float sw[SS];         // 8 KiB: the doc's idf weights
  __shared__ float warr[NW];       // per-wave wsum partials
  __shared__ float red[NW][8][20]; // 5 KiB: cross-wave stat combine

  // Stage the doc's 2048 idf weights (4 gathers/thread); fold the wsum
  // reduction into the same pass via a wave shuffle reduce.
  float wp = 0.f;
#pragma unroll
  for (int i = 0; i < SS / NT; i++) {
    float w = idf[chunk[b * SS + i * NT + tid]];
    sw[i * NT + tid] = w;
    wp += w;
  }
#pragma unroll
  for (int off = 32; off > 0; off >>= 1) wp += __shfl_down(wp, off, 64);
  if (lane == 0) warr[wid] = wp;
  __syncthreads();

  float swe[4] = {0.f, 0.f, 0.f, 0.f};
  float se[4] = {0.f, 0.f, 0.f, 0.f};
  float se2[4] = {0.f, 0.f, 0.f, 0.f};
  float mx[4], mn[4];
#pragma unroll
  for (int k = 0; k < 4; k++) {
    mx[k] = -FLT_BIG;
    mn[k] = FLT_BIG;
  }

  const float* base = enc + ((size_t)b * SS) * DD + sl * CPS + d4 * 4;
#pragma unroll 8
  for (int k = 0; k < SS / 64; k++) {
    int s = srow + 64 * k;
    float w = sw[s];  // 8 distinct consecutive addrs/wave: broadcast, free
    float4 e = *(const float4*)(base + (size_t)s * DD);
    float ev[4] = {e.x, e.y, e.z, e.w};
#pragma unroll
    for (int j = 0; j < 4; j++) {
      swe[j] = fmaf(w, ev[j], swe[j]);
      se[j] += ev[j];
      se2[j] = fmaf(ev[j], ev[j], se2[j]);
      mx[j] = fmaxf(mx[j], ev[j]);
      mn[j] = fminf(mn[j], ev[j]);
    }
  }

  // Combine the 8 srow-groups within each wave (lanes sharing d4 are
  // l, l^8, l^16, ..., l^56). Butterfly over xor 32, 16, 8.
#pragma unroll
  for (int j = 0; j < 4; j++) {
    swe[j] += __shfl_xor(swe[j], 32, 64);
    swe[j] += __shfl_xor(swe[j], 16, 64);
    swe[j] += __shfl_xor(swe[j], 8, 64);
    se[j] += __shfl_xor(se[j], 32, 64);
    se[j] += __shfl_xor(se[j], 16, 64);
    se[j] += __shfl_xor(se[j], 8, 64);
    se2[j] += __shfl_xor(se2[j], 32, 64);
    se2[j] += __shfl_xor(se2[j], 16, 64);
    se2[j] += __shfl_xor(se2[j], 8, 64);
    mx[j] = fmaxf(mx[j], __shfl_xor(mx[j], 32, 64));
    mx[j] = fmaxf(mx[j], __shfl_xor(mx[j], 16, 64));
    mx[j] = fmaxf(mx[j], __shfl_xor(mx[j], 8, 64));
    mn[j] = fminf(mn[j], __shfl_xor(mn[j], 32, 64));
    mn[j] = fminf(mn[j], __shfl_xor(mn[j], 16, 64));
    mn[j] = fminf(mn[j], __shfl_xor(mn[j], 8, 64));
  }
  if (lane < 8) {
    float* r = red[wid][lane];
#pragma unroll
    for (int j = 0; j < 4; j++) {
      r[j] = swe[j];
      r[4 + j] = se[j];
      r[8 + j] = se2[j];
      r[12 + j] = mx[j];
      r[16 + j] = mn[j];
    }
  }
  __syncthreads();

  // 32 threads finish the slice: column c -> (float4 f4, component comp).
  if (tid < CPS) {
    int f4 = tid >> 2, comp = tid & 3;
    float cswe = 0.f, cse = 0.f, cse2 = 0.f, wtot = 0.f;
    float cmx = -FLT_BIG, cmn = FLT_BIG;
#pragma unroll
    for (int wv = 0; wv < NW; wv++) {
      const float* r = red[wv][f4];
      cswe += r[comp];
      cse += r[4 + comp];
      cse2 += r[8 + comp];
      cmx = fmaxf(cmx, r[12 + comp]);
      cmn = fminf(cmn, r[16 + comp]);
      wtot += warr[wv];
    }
    float mu = cse / (float)SS;
    float stdv =
        sqrtf(fmaxf((cse2 - (float)SS * mu * mu) / (float)(SS - 1), 0.f));
    int d = sl * CPS + tid;
    size_t ob = (size_t)b * 4 * DD;
    out[ob + d] = cswe / wtot;
    out[ob + DD + d] = cmx;
    out[ob + 2 * DD + d] = cmn;
    out[ob + 3 * DD + d] = stdv;
  }
}

extern "C" void kernel_launch(void* const* d_in, const int* in_sizes, int n_in,
                              void* d_out, int out_size, void* d_ws,
                              size_t ws_size, hipStream_t stream) {
  const int* chunk = (const int*)d_in[0];
  const float* enc = (const float*)d_in[1];
  const float* idf = (const float*)d_in[2];
  float* out = (float*)d_out;

  fused_kernel<<<dim3(NSL, BB), NT, 0, stream>>>(chunk, enc, idf, out);
}